// Round 7
// baseline (99.153 us; speedup 1.0000x reference)
//
#include <hip/hip_runtime.h>
#include <hip/hip_bf16.h>

#define N 8192
#define D 128
#define LOG2E  1.44269504088896f
#define LN2    0.69314718055995f

#define COLSB   272                // padded bytes per staged column (256 + 16)
#define NSTEPS  4                  // 128 cols per block / 32 cols per step

typedef __attribute__((ext_vector_type(8))) short bf16x8;
typedef __attribute__((ext_vector_type(4))) float f32x4;

#if __has_builtin(__builtin_amdgcn_exp2f)
#define EXP2(x) __builtin_amdgcn_exp2f(x)
#else
#define EXP2(x) exp2f(x)
#endif
#if __has_builtin(__builtin_amdgcn_logf)
#define LOG2(x) __builtin_amdgcn_logf(x)
#else
#define LOG2(x) log2f(x)
#endif

static __device__ __forceinline__ unsigned short f2bf(float f) {
    union { float f; unsigned int u; } x;
    x.f = f;
    unsigned int r = ((x.u >> 16) & 1u) + 0x7FFFu;  // round-to-nearest-even
    return (unsigned short)((x.u + r) >> 16);
}

// Kernel 1: E (fp32) -> bf16 in ws; zero rowsum accumulator and out[0].
__global__ void prep_kernel(const float* __restrict__ E,
                            unsigned short* __restrict__ Eb,
                            float* __restrict__ rowsum,
                            float* __restrict__ out) {
    int idx = blockIdx.x * 256 + threadIdx.x;   // 262144 threads, 4 elems each
    float4 v = ((const float4*)E)[idx];
    ushort4 o;
    o.x = f2bf(v.x); o.y = f2bf(v.y); o.z = f2bf(v.z); o.w = f2bf(v.w);
    ((ushort4*)Eb)[idx] = o;
    if (idx < N) rowsum[idx] = 0.0f;
    if (idx == 0) out[0] = 0.0f;
}

// Kernel 2 (R7): SYMMETRY-HALVED fused kernel.
// terms[i][j] == terms[j][i] (sim and eq are symmetric, same formula), so
// row sums == col sums. Tile the upper triangle only: 128x128 tiles,
// grid = 64*65/2 = 2080 blocks, 128 threads = 2 waves x 64 rows.
// Off-diagonal tiles credit each term to BOTH rowsum[row] (register acc,
// end-of-kernel atomic) and rowsum[col] (per-subtile q-shuffle reduce +
// one 16-lane coalesced atomic). Diagonal tiles: rows only.
// Keeps R6's LDS double-buffered staging (4 steps x 32 cols, stride 272B)
// and all VGPR lessons: t-loop pinned rolled (R4), no min-waves bound (R2),
// heavy epilogue stays out (R3).
__global__ __launch_bounds__(128) void fused_kernel(
        const unsigned short* __restrict__ Eb,
        const int* __restrict__ labels,
        float* __restrict__ rowsum) {
    __shared__ __align__(16) char ldsbuf[2][32 * COLSB];   // 17408 B

    const int tid  = threadIdx.x;
    const int wid  = tid >> 6;     // 0..1
    const int lane = tid & 63;
    const int q = lane >> 4;       // 0..3
    const int l = lane & 15;       // 0..15

    // Decode triangular tile index b -> (r, c) with r <= c, 64 row-tiles.
    // f(r) = blocks before row r = 64r - r(r-1)/2.
    const int b = blockIdx.x;
    int r = (int)(64.5f - sqrtf(64.5f * 64.5f - 2.0f * (float)b));
    while ((r + 1) * 64 - ((r + 1) * r) / 2 <= b) ++r;
    while (r * 64 - (r * (r - 1)) / 2 > b) --r;
    const int c = r + (b - (r * 64 - (r * (r - 1)) / 2));
    const bool diag = (r == c);
    const int m0 = r * 128 + wid * 64;
    const int n_begin = c * 128;

    // A fragments: a[g][kk] = E[m0+g*16+l][kk*32 + q*8 .. +7]
    bf16x8 a[4][4];
#pragma unroll
    for (int g = 0; g < 4; ++g) {
        const bf16x8* p = (const bf16x8*)(Eb + (size_t)(m0 + g * 16 + l) * D + q * 8);
#pragma unroll
        for (int kk = 0; kk < 4; ++kk) a[g][kk] = p[kk * 4];
    }

    // Row labels for the 16 output rows this lane owns (row = g*16 + q*4 + r).
    int lrow[16];
#pragma unroll
    for (int g = 0; g < 4; ++g)
#pragma unroll
        for (int rr = 0; rr < 4; ++rr)
            lrow[g * 4 + rr] = labels[m0 + g * 16 + q * 4 + rr];

    float sum[16];
#pragma unroll
    for (int i = 0; i < 16; ++i) sum[i] = 0.0f;

    // ---- staging: step tile = 32 cols x 256 B = 8 KB; 128 thr x 64 B ----
    const char* gB = (const char*)Eb + (size_t)n_begin * 256;
    const int gofs = tid * 64;
    const int lofs = (tid >> 2) * COLSB + (tid & 3) * 64;

    float4 v0, v1, v2, v3;
    {   // prologue: stage step 0, issue load of step 1
        const float4* p = (const float4*)(gB + gofs);
        v0 = p[0]; v1 = p[1]; v2 = p[2]; v3 = p[3];
        float4* dst = (float4*)(&ldsbuf[0][lofs]);
        dst[0] = v0; dst[1] = v1; dst[2] = v2; dst[3] = v3;
        const float4* p1 = (const float4*)(gB + 32 * 256 + gofs);
        v0 = p1[0]; v1 = p1[1]; v2 = p1[2]; v3 = p1[3];
    }
    __syncthreads();

#pragma clang loop unroll(disable)
    for (int t = 0; t < NSTEPS; ++t) {
        if (t + 1 < NSTEPS) {
            float4* dst = (float4*)(&ldsbuf[(t + 1) & 1][lofs]);
            dst[0] = v0; dst[1] = v1; dst[2] = v2; dst[3] = v3;
        }
        if (t + 2 < NSTEPS) {
            const float4* p = (const float4*)(gB + (size_t)(t + 2) * 32 * 256 + gofs);
            v0 = p[0]; v1 = p[1]; v2 = p[2]; v3 = p[3];
        }

        // compute on buffer t&1: 2 subtiles of 16 cols
#pragma unroll
        for (int s = 0; s < 2; ++s) {
            const int col = n_begin + t * 32 + s * 16 + l;
            const int lc = labels[col];
            const char* lb = &ldsbuf[t & 1][(s * 16 + l) * COLSB + q * 16];
            bf16x8 b0 = *(const bf16x8*)(lb);
            bf16x8 b1 = *(const bf16x8*)(lb + 64);
            bf16x8 b2 = *(const bf16x8*)(lb + 128);
            bf16x8 b3 = *(const bf16x8*)(lb + 192);

            f32x4 acc[4];
#pragma unroll
            for (int g = 0; g < 4; ++g) {
                acc[g] = (f32x4){0.f, 0.f, 0.f, 0.f};
                acc[g] = __builtin_amdgcn_mfma_f32_16x16x32_bf16(a[g][0], b0, acc[g], 0, 0, 0);
                acc[g] = __builtin_amdgcn_mfma_f32_16x16x32_bf16(a[g][1], b1, acc[g], 0, 0, 0);
                acc[g] = __builtin_amdgcn_mfma_f32_16x16x32_bf16(a[g][2], b2, acc[g], 0, 0, 0);
                acc[g] = __builtin_amdgcn_mfma_f32_16x16x32_bf16(a[g][3], b3, acc[g], 0, 0, 0);
            }

            // term = exp2(cc * (sim - margin)); cc = eq ? -log2e : +log2e
            float cp = 0.0f;
#pragma unroll
            for (int g = 0; g < 4; ++g) {
#pragma unroll
                for (int rr = 0; rr < 4; ++rr) {
                    float sv = acc[g][rr];
                    bool eq = (lrow[g * 4 + rr] == lc);
                    float cc = eq ? -LOG2E : LOG2E;
                    float term = EXP2(cc * (sv - 0.1f));
                    sum[g * 4 + rr] += term;
                    cp += term;
                }
            }
            if (!diag) {
                // column contribution: reduce over the 4 q-quarters
                cp += __shfl_xor(cp, 16);
                cp += __shfl_xor(cp, 32);
                if (q == 0) atomicAdd(&rowsum[col], cp);
            }
        }
        __syncthreads();
    }

    // Row contributions: reduce across the 16 column-lanes.
#pragma unroll
    for (int i = 0; i < 16; ++i) {
        float v = sum[i];
        v += __shfl_xor(v, 1);
        v += __shfl_xor(v, 2);
        v += __shfl_xor(v, 4);
        v += __shfl_xor(v, 8);
        sum[i] = v;
    }
    if (l == 0) {
#pragma unroll
        for (int g = 0; g < 4; ++g)
#pragma unroll
            for (int rr = 0; rr < 4; ++rr)
                atomicAdd(&rowsum[m0 + g * 16 + q * 4 + rr], sum[g * 4 + rr]);
    }
}

// Kernel 3: out += sum_i log(rowsum[i]) / N, 32 blocks of 256.
__global__ void finalize_kernel(const float* __restrict__ rowsum, float* __restrict__ out) {
    __shared__ float red[4];
    int i = blockIdx.x * 256 + threadIdx.x;
    float v = LOG2(rowsum[i]) * LN2;
#pragma unroll
    for (int off = 1; off <= 32; off <<= 1) v += __shfl_xor(v, off);
    if ((threadIdx.x & 63) == 0) red[threadIdx.x >> 6] = v;
    __syncthreads();
    if (threadIdx.x == 0)
        atomicAdd(out, (red[0] + red[1] + red[2] + red[3]) * (1.0f / (float)N));
}

extern "C" void kernel_launch(void* const* d_in, const int* in_sizes, int n_in,
                              void* d_out, int out_size, void* d_ws, size_t ws_size,
                              hipStream_t stream) {
    const float* E = (const float*)d_in[0];
    const int* labels = (const int*)d_in[1];
    float* out = (float*)d_out;

    unsigned short* Eb = (unsigned short*)d_ws;                                     // 2 MiB
    float* rowsum = (float*)((char*)d_ws + (size_t)N * D * sizeof(unsigned short)); // 32 KiB

    prep_kernel<<<1024, 256, 0, stream>>>(E, Eb, rowsum, out);
    fused_kernel<<<2080, 128, 0, stream>>>(Eb, labels, rowsum);
    finalize_kernel<<<32, 256, 0, stream>>>(rowsum, out);
}

// Round 8
// 90.882 us; speedup vs baseline: 1.0910x; 1.0910x over previous
//
#include <hip/hip_runtime.h>
#include <hip/hip_bf16.h>

#define N 8192
#define D 128
#define LOG2E  1.44269504088896f
#define LN2    0.69314718055995f
#define COLSB  272                 // padded LDS bytes per staged column

typedef __attribute__((ext_vector_type(8))) short bf16x8;
typedef __attribute__((ext_vector_type(4))) float f32x4;

#if __has_builtin(__builtin_amdgcn_exp2f)
#define EXP2(x) __builtin_amdgcn_exp2f(x)
#else
#define EXP2(x) exp2f(x)
#endif
#if __has_builtin(__builtin_amdgcn_logf)
#define LOG2(x) __builtin_amdgcn_logf(x)
#else
#define LOG2(x) log2f(x)
#endif

static __device__ __forceinline__ unsigned short f2bf(float f) {
    union { float f; unsigned int u; } x;
    x.f = f;
    unsigned int r = ((x.u >> 16) & 1u) + 0x7FFFu;  // round-to-nearest-even
    return (unsigned short)((x.u + r) >> 16);
}

// Kernel 1: E (fp32) -> bf16 in ws; zero rowsum accumulator and out[0].
__global__ void prep_kernel(const float* __restrict__ E,
                            unsigned short* __restrict__ Eb,
                            float* __restrict__ rowsum,
                            float* __restrict__ out) {
    int idx = blockIdx.x * 256 + threadIdx.x;   // 262144 threads, 4 elems each
    float4 v = ((const float4*)E)[idx];
    ushort4 o;
    o.x = f2bf(v.x); o.y = f2bf(v.y); o.z = f2bf(v.z); o.w = f2bf(v.w);
    ((ushort4*)Eb)[idx] = o;
    if (idx < N) rowsum[idx] = 0.0f;
    if (idx == 0) out[0] = 0.0f;
}

// Kernel 2 (R8): ONE global phase, ONE barrier, then pure LDS compute.
// R6/R7 evidence: fused time identical (~43us) with full vs half compute ->
// blocks live in L2-congestion latency chains, one per pipeline step (each
// __syncthreads drains vmcnt(0)). Fix: issue ALL global loads for the block
// in a single burst (A-frags -> VGPR, 32KB B-tile -> VGPR, 256 labels),
// one LDS write burst, one barrier, then 8 subtiles of LDS+MFMA+exp with
// zero further global dependency. Triangular symmetry kept (row+col credit);
// col credits accumulate in LDS, flushed once per block.
// Tile 128x128, 256 thr = 4 waves, wave owns 32 rows (a[2][4], low VGPR).
// LDS 36352B -> 4 blocks/CU. s-loop pinned rolled (R4 lesson); no min-waves
// bound (R2); heavy epilogue out of allocator's way (R3).
__global__ __launch_bounds__(256) void fused_kernel(
        const unsigned short* __restrict__ Eb,
        const int* __restrict__ labels,
        float* __restrict__ rowsum) {
    __shared__ __align__(16) char bB[128 * COLSB];   // 34816 B
    __shared__ int   labC[128];
    __shared__ int   labR[128];
    __shared__ float colacc[128];

    const int tid  = threadIdx.x;
    const int wid  = tid >> 6;     // 0..3
    const int lane = tid & 63;
    const int q = lane >> 4;       // 0..3
    const int l = lane & 15;       // 0..15

    // Triangular tile decode b -> (r, c), r <= c, 64 row-tiles (128 wide).
    const int b = blockIdx.x;
    int r = (int)(64.5f - sqrtf(64.5f * 64.5f - 2.0f * (float)b));
    while ((r + 1) * 64 - ((r + 1) * r) / 2 <= b) ++r;
    while (r * 64 - (r * (r - 1)) / 2 > b) --r;
    const int c = r + (b - (r * 64 - (r * (r - 1)) / 2));
    const bool diag = (r == c);
    const int tile_m0 = r * 128;
    const int n_begin = c * 128;
    const int mrow0 = tile_m0 + wid * 32;   // this wave's 32-row strip

    // ---- single global burst: A-frags, B-tile, labels ----
    // A: a[g][kk] = E[mrow0+g*16+l][kk*32 + q*8 .. +7]   (8 b128 loads)
    bf16x8 a[2][4];
#pragma unroll
    for (int g = 0; g < 2; ++g) {
        const bf16x8* p = (const bf16x8*)(Eb + (size_t)(mrow0 + g * 16 + l) * D + q * 8);
#pragma unroll
        for (int kk = 0; kk < 4; ++kk) a[g][kk] = p[kk * 4];
    }
    // B: 128 cols x 256 B; thread handles half a column (128 B = 8 float4).
    const char* gB = (const char*)Eb + (size_t)n_begin * 256;
    const int col  = tid >> 1;
    const int half = tid & 1;
    const float4* src = (const float4*)(gB + col * 256 + half * 128);
    float4 st[8];
#pragma unroll
    for (int i = 0; i < 8; ++i) st[i] = src[i];
    // labels (col for tid<128, row otherwise)
    int labv = (tid < 128) ? labels[n_begin + tid]
                           : labels[tile_m0 + (tid - 128)];

    // ---- LDS write burst ----
    float4* dst = (float4*)(bB + col * COLSB + half * 128);
#pragma unroll
    for (int i = 0; i < 8; ++i) dst[i] = st[i];
    if (tid < 128) { labC[tid] = labv; colacc[tid] = 0.0f; }
    else           { labR[tid - 128] = labv; }
    __syncthreads();   // the ONLY barrier before compute

    // Row labels for this lane's 8 output rows (row = g*16 + q*4 + rr).
    int lrow[8];
#pragma unroll
    for (int g = 0; g < 2; ++g)
#pragma unroll
        for (int rr = 0; rr < 4; ++rr)
            lrow[g * 4 + rr] = labR[wid * 32 + g * 16 + q * 4 + rr];

    float sum[8];
#pragma unroll
    for (int i = 0; i < 8; ++i) sum[i] = 0.0f;

    // ---- compute: 8 subtiles of 16 cols, all from LDS ----
#pragma clang loop unroll(disable)
    for (int s = 0; s < 8; ++s) {
        const int lc = labC[s * 16 + l];
        const char* lb = bB + (s * 16 + l) * COLSB + q * 16;
        bf16x8 b0 = *(const bf16x8*)(lb);
        bf16x8 b1 = *(const bf16x8*)(lb + 64);
        bf16x8 b2 = *(const bf16x8*)(lb + 128);
        bf16x8 b3 = *(const bf16x8*)(lb + 192);

        f32x4 acc0 = (f32x4){0.f, 0.f, 0.f, 0.f};
        f32x4 acc1 = (f32x4){0.f, 0.f, 0.f, 0.f};
        acc0 = __builtin_amdgcn_mfma_f32_16x16x32_bf16(a[0][0], b0, acc0, 0, 0, 0);
        acc0 = __builtin_amdgcn_mfma_f32_16x16x32_bf16(a[0][1], b1, acc0, 0, 0, 0);
        acc0 = __builtin_amdgcn_mfma_f32_16x16x32_bf16(a[0][2], b2, acc0, 0, 0, 0);
        acc0 = __builtin_amdgcn_mfma_f32_16x16x32_bf16(a[0][3], b3, acc0, 0, 0, 0);
        acc1 = __builtin_amdgcn_mfma_f32_16x16x32_bf16(a[1][0], b0, acc1, 0, 0, 0);
        acc1 = __builtin_amdgcn_mfma_f32_16x16x32_bf16(a[1][1], b1, acc1, 0, 0, 0);
        acc1 = __builtin_amdgcn_mfma_f32_16x16x32_bf16(a[1][2], b2, acc1, 0, 0, 0);
        acc1 = __builtin_amdgcn_mfma_f32_16x16x32_bf16(a[1][3], b3, acc1, 0, 0, 0);

        // term = exp2(cc*(sim-margin)); credit row (reg) and col (LDS).
        float cp = 0.0f;
#pragma unroll
        for (int g = 0; g < 2; ++g) {
#pragma unroll
            for (int rr = 0; rr < 4; ++rr) {
                float sv = (g == 0) ? acc0[rr] : acc1[rr];
                bool eq = (lrow[g * 4 + rr] == lc);
                float cc = eq ? -LOG2E : LOG2E;
                float term = EXP2(cc * (sv - 0.1f));
                sum[g * 4 + rr] += term;
                cp += term;
            }
        }
        if (!diag) {
            cp += __shfl_xor(cp, 16);   // reduce over q-quarters
            cp += __shfl_xor(cp, 32);
            if (q == 0) atomicAdd(&colacc[s * 16 + l], cp);
        }
    }

    // Row credits: reduce across the 16 column-lanes, one atomic set.
#pragma unroll
    for (int i = 0; i < 8; ++i) {
        float v = sum[i];
        v += __shfl_xor(v, 1);
        v += __shfl_xor(v, 2);
        v += __shfl_xor(v, 4);
        v += __shfl_xor(v, 8);
        sum[i] = v;
    }
    if (l == 0) {
#pragma unroll
        for (int g = 0; g < 2; ++g)
#pragma unroll
            for (int rr = 0; rr < 4; ++rr)
                atomicAdd(&rowsum[mrow0 + g * 16 + q * 4 + rr], sum[g * 4 + rr]);
    }

    // Col credits: one flush per block.
    __syncthreads();
    if (!diag && tid < 128) atomicAdd(&rowsum[n_begin + tid], colacc[tid]);
}

// Kernel 3: out += sum_i log(rowsum[i]) / N, 32 blocks of 256.
__global__ void finalize_kernel(const float* __restrict__ rowsum, float* __restrict__ out) {
    __shared__ float red[4];
    int i = blockIdx.x * 256 + threadIdx.x;
    float v = LOG2(rowsum[i]) * LN2;
#pragma unroll
    for (int off = 1; off <= 32; off <<= 1) v += __shfl_xor(v, off);
    if ((threadIdx.x & 63) == 0) red[threadIdx.x >> 6] = v;
    __syncthreads();
    if (threadIdx.x == 0)
        atomicAdd(out, (red[0] + red[1] + red[2] + red[3]) * (1.0f / (float)N));
}

extern "C" void kernel_launch(void* const* d_in, const int* in_sizes, int n_in,
                              void* d_out, int out_size, void* d_ws, size_t ws_size,
                              hipStream_t stream) {
    const float* E = (const float*)d_in[0];
    const int* labels = (const int*)d_in[1];
    float* out = (float*)d_out;

    unsigned short* Eb = (unsigned short*)d_ws;                                     // 2 MiB
    float* rowsum = (float*)((char*)d_ws + (size_t)N * D * sizeof(unsigned short)); // 32 KiB

    prep_kernel<<<1024, 256, 0, stream>>>(E, Eb, rowsum, out);
    fused_kernel<<<2080, 256, 0, stream>>>(Eb, labels, rowsum);
    finalize_kernel<<<32, 256, 0, stream>>>(rowsum, out);
}

// Round 9
// 90.031 us; speedup vs baseline: 1.1013x; 1.0095x over previous
//
#include <hip/hip_runtime.h>
#include <hip/hip_bf16.h>

#define N 8192
#define D 128
#define LOG2E  1.44269504088896f
#define LN2    0.69314718055995f
#define COLSB  272                 // padded LDS bytes per staged column

typedef __attribute__((ext_vector_type(8))) short bf16x8;
typedef __attribute__((ext_vector_type(4))) float f32x4;

#if __has_builtin(__builtin_amdgcn_exp2f)
#define EXP2(x) __builtin_amdgcn_exp2f(x)
#else
#define EXP2(x) exp2f(x)
#endif
#if __has_builtin(__builtin_amdgcn_logf)
#define LOG2(x) __builtin_amdgcn_logf(x)
#else
#define LOG2(x) log2f(x)
#endif

static __device__ __forceinline__ unsigned short f2bf(float f) {
    union { float f; unsigned int u; } x;
    x.f = f;
    unsigned int r = ((x.u >> 16) & 1u) + 0x7FFFu;  // round-to-nearest-even
    return (unsigned short)((x.u + r) >> 16);
}

// Kernel 1: E (fp32) -> bf16 in ws; zero ticket counter.
__global__ void prep_kernel(const float* __restrict__ E,
                            unsigned short* __restrict__ Eb,
                            unsigned int* __restrict__ counter) {
    int idx = blockIdx.x * 256 + threadIdx.x;   // 262144 threads, 4 elems each
    float4 v = ((const float4*)E)[idx];
    ushort4 o;
    o.x = f2bf(v.x); o.y = f2bf(v.y); o.z = f2bf(v.z); o.w = f2bf(v.w);
    ((ushort4*)Eb)[idx] = o;
    if (idx == 0) *counter = 0u;
}

// Kernel 2 (R9): R8 structure, ZERO global atomics.
// R8 post-mortem: halving compute (R7) and collapsing barriers (R8) left
// ~25us of non-issue time in fused -> prime suspect is the 532K device-scope
// fp32 atomics onto 512 cache lines (~1000 serialized ops/line at the
// device-coherent home point). Fix: symmetry gives every output cell exactly
// ONE writer. Block (r,c): row-credits -> part[c][128r..128r+128) (plain
// stores), col-credits -> part[r][128c..128c+128) (plain stores; diag skips
// col side, its row-credits fill plane part[r][tile r]). part is 64x8192 f32
// (2 MiB in ws), written exactly once per cell, never zeroed, never atomic.
// Finalize sums the 64 planes. All prior lessons kept: one barrier before
// compute, s-loop rolled (R4), no min-waves bound (R2), tiny epilogue (R3).
__global__ __launch_bounds__(256) void fused_kernel(
        const unsigned short* __restrict__ Eb,
        const int* __restrict__ labels,
        float* __restrict__ part) {
    __shared__ __align__(16) char bB[128 * COLSB];   // 34816 B
    __shared__ int   labC[128];
    __shared__ int   labR[128];
    __shared__ float colacc[128];

    const int tid  = threadIdx.x;
    const int wid  = tid >> 6;     // 0..3
    const int lane = tid & 63;
    const int q = lane >> 4;       // 0..3
    const int l = lane & 15;       // 0..15

    // Triangular tile decode b -> (r, c), r <= c, 64 row-tiles (128 wide).
    const int b = blockIdx.x;
    int r = (int)(64.5f - sqrtf(64.5f * 64.5f - 2.0f * (float)b));
    while ((r + 1) * 64 - ((r + 1) * r) / 2 <= b) ++r;
    while (r * 64 - (r * (r - 1)) / 2 > b) --r;
    const int c = r + (b - (r * 64 - (r * (r - 1)) / 2));
    const bool diag = (r == c);
    const int tile_m0 = r * 128;
    const int n_begin = c * 128;
    const int mrow0 = tile_m0 + wid * 32;   // this wave's 32-row strip

    // ---- single global burst: A-frags, B-tile, labels ----
    bf16x8 a[2][4];
#pragma unroll
    for (int g = 0; g < 2; ++g) {
        const bf16x8* p = (const bf16x8*)(Eb + (size_t)(mrow0 + g * 16 + l) * D + q * 8);
#pragma unroll
        for (int kk = 0; kk < 4; ++kk) a[g][kk] = p[kk * 4];
    }
    const char* gB = (const char*)Eb + (size_t)n_begin * 256;
    const int col  = tid >> 1;
    const int half = tid & 1;
    const float4* src = (const float4*)(gB + col * 256 + half * 128);
    float4 st[8];
#pragma unroll
    for (int i = 0; i < 8; ++i) st[i] = src[i];
    int labv = (tid < 128) ? labels[n_begin + tid]
                           : labels[tile_m0 + (tid - 128)];

    // ---- LDS write burst ----
    float4* dst = (float4*)(bB + col * COLSB + half * 128);
#pragma unroll
    for (int i = 0; i < 8; ++i) dst[i] = st[i];
    if (tid < 128) { labC[tid] = labv; colacc[tid] = 0.0f; }
    else           { labR[tid - 128] = labv; }
    __syncthreads();   // the ONLY barrier before compute

    int lrow[8];
#pragma unroll
    for (int g = 0; g < 2; ++g)
#pragma unroll
        for (int rr = 0; rr < 4; ++rr)
            lrow[g * 4 + rr] = labR[wid * 32 + g * 16 + q * 4 + rr];

    float sum[8];
#pragma unroll
    for (int i = 0; i < 8; ++i) sum[i] = 0.0f;

    // ---- compute: 8 subtiles of 16 cols, all from LDS ----
#pragma clang loop unroll(disable)
    for (int s = 0; s < 8; ++s) {
        const int lc = labC[s * 16 + l];
        const char* lb = bB + (s * 16 + l) * COLSB + q * 16;
        bf16x8 b0 = *(const bf16x8*)(lb);
        bf16x8 b1 = *(const bf16x8*)(lb + 64);
        bf16x8 b2 = *(const bf16x8*)(lb + 128);
        bf16x8 b3 = *(const bf16x8*)(lb + 192);

        f32x4 acc0 = (f32x4){0.f, 0.f, 0.f, 0.f};
        f32x4 acc1 = (f32x4){0.f, 0.f, 0.f, 0.f};
        acc0 = __builtin_amdgcn_mfma_f32_16x16x32_bf16(a[0][0], b0, acc0, 0, 0, 0);
        acc0 = __builtin_amdgcn_mfma_f32_16x16x32_bf16(a[0][1], b1, acc0, 0, 0, 0);
        acc0 = __builtin_amdgcn_mfma_f32_16x16x32_bf16(a[0][2], b2, acc0, 0, 0, 0);
        acc0 = __builtin_amdgcn_mfma_f32_16x16x32_bf16(a[0][3], b3, acc0, 0, 0, 0);
        acc1 = __builtin_amdgcn_mfma_f32_16x16x32_bf16(a[1][0], b0, acc1, 0, 0, 0);
        acc1 = __builtin_amdgcn_mfma_f32_16x16x32_bf16(a[1][1], b1, acc1, 0, 0, 0);
        acc1 = __builtin_amdgcn_mfma_f32_16x16x32_bf16(a[1][2], b2, acc1, 0, 0, 0);
        acc1 = __builtin_amdgcn_mfma_f32_16x16x32_bf16(a[1][3], b3, acc1, 0, 0, 0);

        float cp = 0.0f;
#pragma unroll
        for (int g = 0; g < 2; ++g) {
#pragma unroll
            for (int rr = 0; rr < 4; ++rr) {
                float sv = (g == 0) ? acc0[rr] : acc1[rr];
                bool eq = (lrow[g * 4 + rr] == lc);
                float cc = eq ? -LOG2E : LOG2E;
                float term = EXP2(cc * (sv - 0.1f));
                sum[g * 4 + rr] += term;
                cp += term;
            }
        }
        if (!diag) {
            cp += __shfl_xor(cp, 16);   // reduce over q-quarters
            cp += __shfl_xor(cp, 32);
            if (q == 0) atomicAdd(&colacc[s * 16 + l], cp);  // LDS only
        }
    }

    // Row credits: reduce across the 16 column-lanes, PLAIN stores to plane c.
#pragma unroll
    for (int i = 0; i < 8; ++i) {
        float v = sum[i];
        v += __shfl_xor(v, 1);
        v += __shfl_xor(v, 2);
        v += __shfl_xor(v, 4);
        v += __shfl_xor(v, 8);
        sum[i] = v;
    }
    if (l == 0) {
#pragma unroll
        for (int g = 0; g < 2; ++g)
#pragma unroll
            for (int rr = 0; rr < 4; ++rr)
                part[(size_t)c * N + mrow0 + g * 16 + q * 4 + rr] = sum[g * 4 + rr];
    }

    // Col credits: PLAIN stores to plane r (off-diagonal only).
    __syncthreads();
    if (!diag && tid < 128)
        part[(size_t)r * N + n_begin + tid] = colacc[tid];
}

// Kernel 3: rowsum_i = sum over 64 planes; v = log(rowsum); block-reduce;
// last block (ticket) sums the 32 block partials and writes out.
__global__ void finalize_kernel(const float* __restrict__ part,
                                float* __restrict__ bpart,
                                unsigned int* __restrict__ counter,
                                float* __restrict__ out) {
    __shared__ float red[4];
    __shared__ unsigned int tk;
    const int tid = threadIdx.x;
    const int i = blockIdx.x * 256 + tid;

    float s = 0.0f;
#pragma unroll 8
    for (int x = 0; x < 64; ++x) s += part[(size_t)x * N + i];
    float v = LOG2(s) * LN2;
#pragma unroll
    for (int off = 1; off <= 32; off <<= 1) v += __shfl_xor(v, off);
    if ((tid & 63) == 0) red[tid >> 6] = v;
    __syncthreads();
    if (tid == 0) {
        bpart[blockIdx.x] = red[0] + red[1] + red[2] + red[3];
        __threadfence();                       // release bpart store
        tk = atomicAdd(counter, 1u);
    }
    __syncthreads();
    if (tk == 31u) {                           // last block finalizes
        __threadfence();                       // acquire
        if (tid < 64) {
            float t = (tid < 32)
                ? __hip_atomic_load(&bpart[tid], __ATOMIC_RELAXED,
                                    __HIP_MEMORY_SCOPE_AGENT)
                : 0.0f;
#pragma unroll
            for (int off = 1; off <= 32; off <<= 1) t += __shfl_xor(t, off);
            if (tid == 0) out[0] = t * (1.0f / (float)N);
        }
    }
}

extern "C" void kernel_launch(void* const* d_in, const int* in_sizes, int n_in,
                              void* d_out, int out_size, void* d_ws, size_t ws_size,
                              hipStream_t stream) {
    const float* E = (const float*)d_in[0];
    const int* labels = (const int*)d_in[1];
    float* out = (float*)d_out;

    unsigned short* Eb = (unsigned short*)d_ws;                 // 2 MiB
    float* part = (float*)((char*)d_ws + (size_t)N * D * 2);    // 64*8192*4 = 2 MiB
    float* bpart = part + (size_t)64 * N;                       // 32 floats
    unsigned int* counter = (unsigned int*)(bpart + 32);        // 4 B

    prep_kernel<<<1024, 256, 0, stream>>>(E, Eb, counter);
    fused_kernel<<<2080, 256, 0, stream>>>(Eb, labels, part);
    finalize_kernel<<<32, 256, 0, stream>>>(part, bpart, counter, out);
}